// Round 12
// baseline (922.605 us; speedup 1.0000x reference)
//
#include <hip/hip_runtime.h>
#include <math.h>

#define LN 8      // layers
#define NRBF 256
#define FD 16
#define OUTD 3
#define KC (-0.72134752044f)   // -0.5 * log2(e)

typedef __attribute__((ext_vector_type(8))) short short8;   // 8 x bf16
typedef __attribute__((ext_vector_type(4))) float floatx4;
typedef __attribute__((ext_vector_type(2))) float floatx2;

__device__ __forceinline__ short f2bf(float f) {
    unsigned u = __builtin_bit_cast(unsigned, f);
    u += 0x7fffu + ((u >> 16) & 1u);          // RNE
    return (short)(u >> 16);
}

// Workspace (j-OUTER layouts so per-j slices are contiguous):
//   PKB: short8[(j*16+nt)*64 + lane]  (128 KB; 16 KB per j)  B-fragments:
//        n = nt*16+(lane&15), k = (lane>>4)*8+e, m=k>>1 -> {A, -2*A*C}
//   EPI: float4[(j*16+nt)*16 + l]    (32 KB; 4 KB per j)  {KC*t3prefix, w0, w1, w2}

__global__ __launch_bounds__(256) void prep(
    const float* __restrict__ centers, const float* __restrict__ betas,
    const float* __restrict__ W, short* __restrict__ PKB, float* __restrict__ EPI)
{
    __shared__ float ls[LN * 32];
    int blk = blockIdx.x;
    int tid = threadIdx.x;
    if (blk < 32) {
        int t = blk * 256 + tid;           // t = j*1024 + nt*64 + lane (linear!)
        int lane = t & 63;
        int nt   = (t >> 6) & 15;
        int j    = t >> 10;
        int n    = nt * 16 + (lane & 15);
        int kq   = lane >> 4;
        size_t base = ((size_t)(j * NRBF + n)) * FD + kq * 4;
        float4 bq = *(const float4*)(betas + base);
        float4 cq = *(const float4*)(centers + base);
        float a0 = __expf(bq.x), a1 = __expf(bq.y), a2 = __expf(bq.z), a3 = __expf(bq.w);
        short8 v;
        v[0] = f2bf(a0); v[1] = f2bf(-2.0f * a0 * cq.x);
        v[2] = f2bf(a1); v[3] = f2bf(-2.0f * a1 * cq.y);
        v[4] = f2bf(a2); v[5] = f2bf(-2.0f * a2 * cq.z);
        v[6] = f2bf(a3); v[7] = f2bf(-2.0f * a3 * cq.w);
        *((short8*)(PKB + (size_t)t * 8)) = v;
    } else {
        int jj = tid >> 5;                  // 0..7
        int nl = tid & 31;
        int n  = (blk - 32) * 32 + nl;
        const float* bp = betas   + ((size_t)(jj * NRBF + n)) * FD;
        const float* cp = centers + ((size_t)(jj * NRBF + n)) * FD;
        float s = 0.f;
#pragma unroll
        for (int q = 0; q < 4; ++q) {
            float4 bq = *(const float4*)(bp + q * 4);
            float4 cq = *(const float4*)(cp + q * 4);
            s = fmaf(__expf(bq.x) * cq.x, cq.x, s);
            s = fmaf(__expf(bq.y) * cq.y, cq.y, s);
            s = fmaf(__expf(bq.z) * cq.z, cq.z, s);
            s = fmaf(__expf(bq.w) * cq.w, cq.w, s);
        }
        ls[jj * 32 + nl] = s;
        __syncthreads();
        float t3 = 0.f;
        for (int j2 = 0; j2 <= jj; ++j2) t3 += ls[j2 * 32 + nl];
        float4 e;
        e.x = KC * t3;
        e.y = W[0 * (LN * NRBF) + jj * NRBF + n];
        e.z = W[1 * (LN * NRBF) + jj * NRBF + n];
        e.w = W[2 * (LN * NRBF) + jj * NRBF + n];
        int nt = n >> 4, l = n & 15;
        ((float4*)EPI)[(jj * 16 + nt) * 16 + l] = e;
    }
}

// 512-thread block = 8 waves = 4 tiles x 2 nt-halves. Each wave owns 8
// prefix accumulators (32 regs) for (tile, half) -- halved footprint vs R11
// so 4 waves/SIMD fit. Per-j PKB/EPI slices shared block-wide, double-
// buffered in LDS via global_load_lds(16B); 8 barriers; cross-half LDS reduce.
__global__ __launch_bounds__(512, 4) void rbf_mfma(
    const float* __restrict__ feats, const short* __restrict__ PKB,
    const float* __restrict__ EPI, const float* __restrict__ bias,
    float* __restrict__ out, int B)
{
    __shared__ short8 pk_s[2][16 * 64];   // 2 x 16 KB
    __shared__ float4 ep_s[2][16 * 16];   // 2 x 4 KB
    __shared__ float  red[8][48];         // 1.5 KB

    int tid  = threadIdx.x;
    int lane = tid & 63;
    int w    = tid >> 6;                  // 0..7
    int tloc = w >> 1;                    // tile within block
    int half = w & 1;                     // nt-half
    int ntile_total = (B + 15) >> 4;
    int tile = blockIdx.x * 4 + tloc;
    bool tvalid = (tile < ntile_total);
    if (!tvalid) tile = ntile_total - 1;  // duplicate work, writes guarded
    int b0 = tile * 16;
    int m  = lane & 15;
    int kq = lane >> 4;

    // A-fragments: lane holds sample b0+m, k-range kq*8.. of each layer
    int brow = b0 + m; if (brow >= B) brow = B - 1;
    const float* xrow = feats + (size_t)brow * (LN * FD) + kq * 4;
    short8 afrag[LN];
#pragma unroll
    for (int j = 0; j < LN; ++j) {
        float4 x = *((const float4*)(xrow + j * FD));
        short8 f;
        f[0] = f2bf(x.x * x.x); f[1] = f2bf(x.x);
        f[2] = f2bf(x.y * x.y); f[3] = f2bf(x.y);
        f[4] = f2bf(x.z * x.z); f[5] = f2bf(x.z);
        f[6] = f2bf(x.w * x.w); f[7] = f2bf(x.w);
        afrag[j] = f;
    }

#define STAGE(buf, jv)                                                          \
    do {                                                                        \
        const short* gp0 = PKB + ((size_t)(jv) * 1024 + (w * 2 + 0) * 64 + lane) * 8; \
        const short* gp1 = PKB + ((size_t)(jv) * 1024 + (w * 2 + 1) * 64 + lane) * 8; \
        __builtin_amdgcn_global_load_lds(                                       \
            (const __attribute__((address_space(1))) void*)gp0,                 \
            (__attribute__((address_space(3))) void*)&pk_s[buf][(w * 2 + 0) * 64], 16, 0, 0); \
        __builtin_amdgcn_global_load_lds(                                       \
            (const __attribute__((address_space(1))) void*)gp1,                 \
            (__attribute__((address_space(3))) void*)&pk_s[buf][(w * 2 + 1) * 64], 16, 0, 0); \
        if (w < 4) {                                                            \
            const float* ge = EPI + ((size_t)(jv) * 256 + w * 64 + lane) * 4;   \
            __builtin_amdgcn_global_load_lds(                                   \
                (const __attribute__((address_space(1))) void*)ge,              \
                (__attribute__((address_space(3))) void*)&ep_s[buf][w * 64], 16, 0, 0); \
        }                                                                       \
    } while (0)

    floatx4 acc[8];
#pragma unroll
    for (int i = 0; i < 8; ++i) acc[i] = (floatx4){0.f, 0.f, 0.f, 0.f};

    floatx2 o01[4];
    float   o2[4];
#pragma unroll
    for (int r = 0; r < 4; ++r) { o01[r] = (floatx2){0.f, 0.f}; o2[r] = 0.f; }

    int ntbase = half * 8;

    STAGE(0, 0);
    __syncthreads();

#pragma unroll
    for (int j = 0; j < LN; ++j) {
        int cur = j & 1;
        if (j < LN - 1) STAGE(cur ^ 1, j + 1);

        // ---- MFMA phase: 8 independent prefix updates (this wave's half) ----
#pragma unroll
        for (int i = 0; i < 8; ++i) {
            short8 bf = pk_s[cur][(ntbase + i) * 64 + lane];
            acc[i] = __builtin_amdgcn_mfma_f32_16x16x32_bf16(afrag[j], bf, acc[i], 0, 0, 0);
        }

        // ---- VALU phase: 32 independent exps + epilogue ----
#pragma unroll
        for (int i = 0; i < 8; ++i) {
            float4 e = ep_s[cur][(ntbase + i) * 16 + m];
            floatx2 eyz = {e.y, e.z};
#pragma unroll
            for (int r = 0; r < 4; ++r) {
                float rv = __builtin_amdgcn_exp2f(fmaf(acc[i][r], KC, e.x));
                o01[r] += (floatx2){rv, rv} * eyz;
                o2[r]   = fmaf(rv, e.w, o2[r]);
            }
        }
        __syncthreads();
    }
#undef STAGE

    // intra-wave reduce over the 16 n-lanes (xor 1,2,4,8 stay within kq group)
    float oacc[12];
#pragma unroll
    for (int r = 0; r < 4; ++r) {
        oacc[r * 3 + 0] = o01[r].x;
        oacc[r * 3 + 1] = o01[r].y;
        oacc[r * 3 + 2] = o2[r];
    }
#pragma unroll
    for (int i = 0; i < 12; ++i) {
        oacc[i] += __shfl_xor(oacc[i], 1);
        oacc[i] += __shfl_xor(oacc[i], 2);
        oacc[i] += __shfl_xor(oacc[i], 4);
        oacc[i] += __shfl_xor(oacc[i], 8);
    }

    if (m < OUTD) {
#pragma unroll
        for (int r = 0; r < 4; ++r)
            red[w][kq * 12 + r * 3 + m] = oacc[r * 3 + m];
    }
    __syncthreads();

    // combine nt-halves: tiles tloc2 = 0..3, 48 outputs each
    if (tid < 192) {
        int tloc2 = tid / 48;
        int q     = tid % 48;
        int tile2 = blockIdx.x * 4 + tloc2;
        if (tile2 < ntile_total) {
            int idx = tile2 * 48 + q;
            if (idx < B * 3) {
                float s = red[tloc2 * 2][q] + red[tloc2 * 2 + 1][q] + bias[q % 3];
                out[idx] = s;
            }
        }
    }
}

extern "C" void kernel_launch(void* const* d_in, const int* in_sizes, int n_in,
                              void* d_out, int out_size, void* d_ws, size_t ws_size,
                              hipStream_t stream) {
    // inputs: 0=x (UNUSED by reference), 1=feats, 2=centers, 3=betas, 4=W, 5=b
    const float* feats   = (const float*)d_in[1];
    const float* centers = (const float*)d_in[2];
    const float* betas   = (const float*)d_in[3];
    const float* W       = (const float*)d_in[4];
    const float* bias    = (const float*)d_in[5];
    float* out = (float*)d_out;
    int B = in_sizes[1] / (LN * FD);

    short* PKB = (short*)d_ws;                       // 65536 shorts = 128 KB
    float* EPI = (float*)((char*)d_ws + 65536 * 2);  // 8192 floats = 32 KB

    prep<<<40, 256, 0, stream>>>(centers, betas, W, PKB, EPI);

    int tiles  = (B + 15) / 16;
    int blocks = (tiles + 3) / 4;
    rbf_mfma<<<blocks, 512, 0, stream>>>(feats, PKB, EPI, bias, out, B);
}

// Round 13
// 168.939 us; speedup vs baseline: 5.4612x; 5.4612x over previous
//
#include <hip/hip_runtime.h>
#include <math.h>

#define LN 8      // layers
#define NRBF 256
#define FD 16
#define OUTD 3
#define KC (-0.72134752044f)   // -0.5 * log2(e)

typedef __attribute__((ext_vector_type(8))) short short8;   // 8 x bf16
typedef __attribute__((ext_vector_type(4))) float floatx4;
typedef __attribute__((ext_vector_type(2))) float floatx2;

__device__ __forceinline__ short f2bf(float f) {
    unsigned u = __builtin_bit_cast(unsigned, f);
    u += 0x7fffu + ((u >> 16) & 1u);          // RNE
    return (short)(u >> 16);
}

// Workspace (j-OUTER layouts so per-j slices are contiguous):
//   PKB: short8[(j*16+nt)*64 + lane]  (128 KB; 16 KB per j)  B-fragments:
//        n = nt*16+(lane&15), k = (lane>>4)*8+e, m=k>>1 -> {A, -2*A*C}
//   EPI: float4[(j*16+nt)*16 + l]    (32 KB; 4 KB per j)  {KC*t3prefix, w0, w1, w2}

__global__ __launch_bounds__(256) void prep(
    const float* __restrict__ centers, const float* __restrict__ betas,
    const float* __restrict__ W, short* __restrict__ PKB, float* __restrict__ EPI)
{
    __shared__ float ls[LN * 32];
    int blk = blockIdx.x;
    int tid = threadIdx.x;
    if (blk < 32) {
        int t = blk * 256 + tid;           // t = j*1024 + nt*64 + lane (linear!)
        int lane = t & 63;
        int nt   = (t >> 6) & 15;
        int j    = t >> 10;
        int n    = nt * 16 + (lane & 15);
        int kq   = lane >> 4;
        size_t base = ((size_t)(j * NRBF + n)) * FD + kq * 4;
        float4 bq = *(const float4*)(betas + base);
        float4 cq = *(const float4*)(centers + base);
        float a0 = __expf(bq.x), a1 = __expf(bq.y), a2 = __expf(bq.z), a3 = __expf(bq.w);
        short8 v;
        v[0] = f2bf(a0); v[1] = f2bf(-2.0f * a0 * cq.x);
        v[2] = f2bf(a1); v[3] = f2bf(-2.0f * a1 * cq.y);
        v[4] = f2bf(a2); v[5] = f2bf(-2.0f * a2 * cq.z);
        v[6] = f2bf(a3); v[7] = f2bf(-2.0f * a3 * cq.w);
        *((short8*)(PKB + (size_t)t * 8)) = v;
    } else {
        int jj = tid >> 5;                  // 0..7
        int nl = tid & 31;
        int n  = (blk - 32) * 32 + nl;
        const float* bp = betas   + ((size_t)(jj * NRBF + n)) * FD;
        const float* cp = centers + ((size_t)(jj * NRBF + n)) * FD;
        float s = 0.f;
#pragma unroll
        for (int q = 0; q < 4; ++q) {
            float4 bq = *(const float4*)(bp + q * 4);
            float4 cq = *(const float4*)(cp + q * 4);
            s = fmaf(__expf(bq.x) * cq.x, cq.x, s);
            s = fmaf(__expf(bq.y) * cq.y, cq.y, s);
            s = fmaf(__expf(bq.z) * cq.z, cq.z, s);
            s = fmaf(__expf(bq.w) * cq.w, cq.w, s);
        }
        ls[jj * 32 + nl] = s;
        __syncthreads();
        float t3 = 0.f;
        for (int j2 = 0; j2 <= jj; ++j2) t3 += ls[j2 * 32 + nl];
        float4 e;
        e.x = KC * t3;
        e.y = W[0 * (LN * NRBF) + jj * NRBF + n];
        e.z = W[1 * (LN * NRBF) + jj * NRBF + n];
        e.w = W[2 * (LN * NRBF) + jj * NRBF + n];
        int nt = n >> 4, l = n & 15;
        ((float4*)EPI)[(jj * 16 + nt) * 16 + l] = e;
    }
}

// 256-thread block = 4 waves = 2 tiles x 2 nt-halves. Each wave owns 8
// prefix accumulators (32 AGPRs) -- halved footprint vs R11 so 4 waves/SIMD.
// Per-j PKB slice (16 KB) double-buffered in LDS via global_load_lds(16B),
// staged block-cooperatively one j ahead; EPI read direct from L2 (off all
// dependency chains). 8 barriers; cross-half reduce via 768 B LDS.
__global__ __launch_bounds__(256, 4) void rbf_mfma(
    const float* __restrict__ feats, const short* __restrict__ PKB,
    const float* __restrict__ EPI, const float* __restrict__ bias,
    float* __restrict__ out, int B)
{
    __shared__ short8 pk_s[2][16 * 64];   // 2 x 16 KB
    __shared__ float  red[4][48];         // 768 B

    int tid  = threadIdx.x;
    int lane = tid & 63;
    int w    = tid >> 6;                  // 0..3
    int tloc = w >> 1;                    // tile within block (0..1)
    int half = w & 1;                     // nt-half
    int ntile_total = (B + 15) >> 4;
    int tile = blockIdx.x * 2 + tloc;
    bool tvalid = (tile < ntile_total);
    if (!tvalid) tile = ntile_total - 1;  // duplicate work, writes guarded
    int b0 = tile * 16;
    int m  = lane & 15;
    int kq = lane >> 4;

    // A-fragments: lane holds sample b0+m, k-range kq*8.. of each layer
    int brow = b0 + m; if (brow >= B) brow = B - 1;
    const float* xrow = feats + (size_t)brow * (LN * FD) + kq * 4;
    short8 afrag[LN];
#pragma unroll
    for (int j = 0; j < LN; ++j) {
        float4 x = *((const float4*)(xrow + j * FD));
        short8 f;
        f[0] = f2bf(x.x * x.x); f[1] = f2bf(x.x);
        f[2] = f2bf(x.y * x.y); f[3] = f2bf(x.y);
        f[4] = f2bf(x.z * x.z); f[5] = f2bf(x.z);
        f[6] = f2bf(x.w * x.w); f[7] = f2bf(x.w);
        afrag[j] = f;
    }

#define STAGE(buf, jv)                                                          \
    do {                                                                        \
        _Pragma("unroll")                                                       \
        for (int i = 0; i < 4; ++i) {                                           \
            const short* gp = PKB + ((size_t)(jv) * 1024 + (w * 4 + i) * 64 + lane) * 8; \
            __builtin_amdgcn_global_load_lds(                                   \
                (const __attribute__((address_space(1))) void*)gp,              \
                (__attribute__((address_space(3))) void*)&pk_s[buf][(w * 4 + i) * 64], \
                16, 0, 0);                                                      \
        }                                                                       \
    } while (0)

    floatx4 acc[8];
#pragma unroll
    for (int i = 0; i < 8; ++i) acc[i] = (floatx4){0.f, 0.f, 0.f, 0.f};

    floatx2 o01[4];
    float   o2[4];
#pragma unroll
    for (int r = 0; r < 4; ++r) { o01[r] = (floatx2){0.f, 0.f}; o2[r] = 0.f; }

    int ntbase = half * 8;
    const float4* epi = (const float4*)EPI + m;   // + (j*16+nt)*16

    STAGE(0, 0);
    __syncthreads();

#pragma unroll
    for (int j = 0; j < LN; ++j) {
        int cur = j & 1;
        if (j < LN - 1) STAGE(cur ^ 1, j + 1);

        // ---- MFMA phase: 8 independent prefix updates (this wave's half) ----
#pragma unroll
        for (int i = 0; i < 8; ++i) {
            short8 bf = pk_s[cur][(ntbase + i) * 64 + lane];
            acc[i] = __builtin_amdgcn_mfma_f32_16x16x32_bf16(afrag[j], bf, acc[i], 0, 0, 0);
        }

        // ---- VALU phase: 32 independent exps + epilogue (EPI from L2) ----
#pragma unroll
        for (int i = 0; i < 8; ++i) {
            float4 e = epi[((size_t)j * 16 + ntbase + i) * 16];
            floatx2 eyz = {e.y, e.z};
#pragma unroll
            for (int r = 0; r < 4; ++r) {
                float rv = __builtin_amdgcn_exp2f(fmaf(acc[i][r], KC, e.x));
                o01[r] += (floatx2){rv, rv} * eyz;
                o2[r]   = fmaf(rv, e.w, o2[r]);
            }
        }
        __syncthreads();
    }
#undef STAGE

    // intra-wave reduce over the 16 n-lanes (xor 1,2,4,8 stay within kq group)
    float oacc[12];
#pragma unroll
    for (int r = 0; r < 4; ++r) {
        oacc[r * 3 + 0] = o01[r].x;
        oacc[r * 3 + 1] = o01[r].y;
        oacc[r * 3 + 2] = o2[r];
    }
#pragma unroll
    for (int i = 0; i < 12; ++i) {
        oacc[i] += __shfl_xor(oacc[i], 1);
        oacc[i] += __shfl_xor(oacc[i], 2);
        oacc[i] += __shfl_xor(oacc[i], 4);
        oacc[i] += __shfl_xor(oacc[i], 8);
    }

    if (m < OUTD) {
#pragma unroll
        for (int r = 0; r < 4; ++r)
            red[w][kq * 12 + r * 3 + m] = oacc[r * 3 + m];
    }
    __syncthreads();

    // combine nt-halves: 2 tiles x 48 outputs
    if (tid < 96) {
        int tloc2 = tid / 48;
        int q     = tid % 48;
        int tile2 = blockIdx.x * 2 + tloc2;
        if (tile2 < ntile_total) {
            int idx = tile2 * 48 + q;
            if (idx < B * 3) {
                float s = red[tloc2 * 2][q] + red[tloc2 * 2 + 1][q] + bias[q % 3];
                out[idx] = s;
            }
        }
    }
}

extern "C" void kernel_launch(void* const* d_in, const int* in_sizes, int n_in,
                              void* d_out, int out_size, void* d_ws, size_t ws_size,
                              hipStream_t stream) {
    // inputs: 0=x (UNUSED by reference), 1=feats, 2=centers, 3=betas, 4=W, 5=b
    const float* feats   = (const float*)d_in[1];
    const float* centers = (const float*)d_in[2];
    const float* betas   = (const float*)d_in[3];
    const float* W       = (const float*)d_in[4];
    const float* bias    = (const float*)d_in[5];
    float* out = (float*)d_out;
    int B = in_sizes[1] / (LN * FD);

    short* PKB = (short*)d_ws;                       // 65536 shorts = 128 KB
    float* EPI = (float*)((char*)d_ws + 65536 * 2);  // 8192 floats = 32 KB

    prep<<<40, 256, 0, stream>>>(centers, betas, W, PKB, EPI);

    int tiles  = (B + 15) / 16;
    int blocks = (tiles + 1) / 2;
    rbf_mfma<<<blocks, 256, 0, stream>>>(feats, PKB, EPI, bias, out, B);
}

// Round 14
// 152.490 us; speedup vs baseline: 6.0503x; 1.1079x over previous
//
#include <hip/hip_runtime.h>
#include <math.h>

#define LN 8      // layers
#define NRBF 256
#define FD 16
#define OUTD 3
#define KC (-0.72134752044f)   // -0.5 * log2(e)

typedef __attribute__((ext_vector_type(8))) short short8;   // 8 x bf16
typedef __attribute__((ext_vector_type(4))) float floatx4;
typedef __attribute__((ext_vector_type(2))) float floatx2;

__device__ __forceinline__ short f2bf(float f) {
    unsigned u = __builtin_bit_cast(unsigned, f);
    u += 0x7fffu + ((u >> 16) & 1u);          // RNE
    return (short)(u >> 16);
}

// Workspace (j-OUTER layouts so per-j slices are contiguous):
//   PKB: short8[(j*16+nt)*64 + lane]  (128 KB; 16 KB per j)  B-fragments:
//        n = nt*16+(lane&15), k = (lane>>4)*8+e, m=k>>1 -> {A, -2*A*C}
//   EPI: float4[(j*16+nt)*16 + l]    (32 KB; 4 KB per j)  {KC*t3prefix, w0, w1, w2}

__global__ __launch_bounds__(256) void prep(
    const float* __restrict__ centers, const float* __restrict__ betas,
    const float* __restrict__ W, short* __restrict__ PKB, float* __restrict__ EPI)
{
    __shared__ float ls[LN * 32];
    int blk = blockIdx.x;
    int tid = threadIdx.x;
    if (blk < 32) {
        int t = blk * 256 + tid;           // t = j*1024 + nt*64 + lane (linear!)
        int lane = t & 63;
        int nt   = (t >> 6) & 15;
        int j    = t >> 10;
        int n    = nt * 16 + (lane & 15);
        int kq   = lane >> 4;
        size_t base = ((size_t)(j * NRBF + n)) * FD + kq * 4;
        float4 bq = *(const float4*)(betas + base);
        float4 cq = *(const float4*)(centers + base);
        float a0 = __expf(bq.x), a1 = __expf(bq.y), a2 = __expf(bq.z), a3 = __expf(bq.w);
        short8 v;
        v[0] = f2bf(a0); v[1] = f2bf(-2.0f * a0 * cq.x);
        v[2] = f2bf(a1); v[3] = f2bf(-2.0f * a1 * cq.y);
        v[4] = f2bf(a2); v[5] = f2bf(-2.0f * a2 * cq.z);
        v[6] = f2bf(a3); v[7] = f2bf(-2.0f * a3 * cq.w);
        *((short8*)(PKB + (size_t)t * 8)) = v;
    } else {
        int jj = tid >> 5;                  // 0..7
        int nl = tid & 31;
        int n  = (blk - 32) * 32 + nl;
        const float* bp = betas   + ((size_t)(jj * NRBF + n)) * FD;
        const float* cp = centers + ((size_t)(jj * NRBF + n)) * FD;
        float s = 0.f;
#pragma unroll
        for (int q = 0; q < 4; ++q) {
            float4 bq = *(const float4*)(bp + q * 4);
            float4 cq = *(const float4*)(cp + q * 4);
            s = fmaf(__expf(bq.x) * cq.x, cq.x, s);
            s = fmaf(__expf(bq.y) * cq.y, cq.y, s);
            s = fmaf(__expf(bq.z) * cq.z, cq.z, s);
            s = fmaf(__expf(bq.w) * cq.w, cq.w, s);
        }
        ls[jj * 32 + nl] = s;
        __syncthreads();
        float t3 = 0.f;
        for (int j2 = 0; j2 <= jj; ++j2) t3 += ls[j2 * 32 + nl];
        float4 e;
        e.x = KC * t3;
        e.y = W[0 * (LN * NRBF) + jj * NRBF + n];
        e.z = W[1 * (LN * NRBF) + jj * NRBF + n];
        e.w = W[2 * (LN * NRBF) + jj * NRBF + n];
        int nt = n >> 4, l = n & 15;
        ((float4*)EPI)[(jj * 16 + nt) * 16 + l] = e;
    }
}

// 256-thread block = 4 waves = 2 tiles x 2 nt-halves; each wave owns 8 prefix
// accumulators (32 AGPR). R11's LDS double-buffer staging (pk+ep) kept intact;
// NO forced reg cap (launch_bounds 256,3) so the VGPR/AGPR split stays natural
// (~90+32 < 128 -> 4 waves/SIMD by actual allocation). LDS exactly 40960 B:
// the cross-half reduce buffer aliases the (dead-after-loop) ep region.
__global__ __launch_bounds__(256, 3) void rbf_mfma(
    const float* __restrict__ feats, const short* __restrict__ PKB,
    const float* __restrict__ EPI, const float* __restrict__ bias,
    float* __restrict__ out, int B)
{
    __shared__ __align__(16) char smem[2 * 16384 + 2 * 4096];   // 40960 B
    short8 (*pk_s)[16 * 64] = (short8(*)[16 * 64])smem;          // 2 x 16 KB
    float4 (*ep_s)[16 * 16] = (float4(*)[16 * 16])(smem + 32768);// 2 x 4 KB
    float* red = (float*)(smem + 32768);                         // alias (768 B)

    int tid  = threadIdx.x;
    int lane = tid & 63;
    int w    = tid >> 6;                  // 0..3
    int tloc = w >> 1;                    // tile within block (0..1)
    int half = w & 1;                     // nt-half
    int ntile_total = (B + 15) >> 4;
    int tile = blockIdx.x * 2 + tloc;
    bool tvalid = (tile < ntile_total);
    if (!tvalid) tile = ntile_total - 1;  // duplicate work, writes guarded
    int b0 = tile * 16;
    int m  = lane & 15;
    int kq = lane >> 4;

    // A-fragments: lane holds sample b0+m, k-range kq*8.. of each layer
    int brow = b0 + m; if (brow >= B) brow = B - 1;
    const float* xrow = feats + (size_t)brow * (LN * FD) + kq * 4;
    short8 afrag[LN];
#pragma unroll
    for (int j = 0; j < LN; ++j) {
        float4 x = *((const float4*)(xrow + j * FD));
        short8 f;
        f[0] = f2bf(x.x * x.x); f[1] = f2bf(x.x);
        f[2] = f2bf(x.y * x.y); f[3] = f2bf(x.y);
        f[4] = f2bf(x.z * x.z); f[5] = f2bf(x.z);
        f[6] = f2bf(x.w * x.w); f[7] = f2bf(x.w);
        afrag[j] = f;
    }

#define STAGE(buf, jv)                                                          \
    do {                                                                        \
        _Pragma("unroll")                                                       \
        for (int i = 0; i < 4; ++i) {                                           \
            const short* gp = PKB + ((size_t)(jv) * 1024 + (w * 4 + i) * 64 + lane) * 8; \
            __builtin_amdgcn_global_load_lds(                                   \
                (const __attribute__((address_space(1))) void*)gp,              \
                (__attribute__((address_space(3))) void*)&pk_s[buf][(w * 4 + i) * 64], \
                16, 0, 0);                                                      \
        }                                                                       \
        const float* ge = EPI + ((size_t)(jv) * 256 + w * 64 + lane) * 4;       \
        __builtin_amdgcn_global_load_lds(                                       \
            (const __attribute__((address_space(1))) void*)ge,                  \
            (__attribute__((address_space(3))) void*)&ep_s[buf][w * 64],        \
            16, 0, 0);                                                          \
    } while (0)

    floatx4 acc[8];
#pragma unroll
    for (int i = 0; i < 8; ++i) acc[i] = (floatx4){0.f, 0.f, 0.f, 0.f};

    floatx2 o01[4];
    float   o2[4];
#pragma unroll
    for (int r = 0; r < 4; ++r) { o01[r] = (floatx2){0.f, 0.f}; o2[r] = 0.f; }

    int ntbase = half * 8;

    STAGE(0, 0);
    __syncthreads();

#pragma unroll
    for (int j = 0; j < LN; ++j) {
        int cur = j & 1;
        if (j < LN - 1) STAGE(cur ^ 1, j + 1);

        // ---- MFMA phase: 8 independent prefix updates (this wave's half) ----
#pragma unroll
        for (int i = 0; i < 8; ++i) {
            short8 bf = pk_s[cur][(ntbase + i) * 64 + lane];
            acc[i] = __builtin_amdgcn_mfma_f32_16x16x32_bf16(afrag[j], bf, acc[i], 0, 0, 0);
        }

        // ---- VALU phase: 32 independent exps + epilogue ----
#pragma unroll
        for (int i = 0; i < 8; ++i) {
            float4 e = ep_s[cur][(ntbase + i) * 16 + m];
            floatx2 eyz = {e.y, e.z};
#pragma unroll
            for (int r = 0; r < 4; ++r) {
                float rv = __builtin_amdgcn_exp2f(fmaf(acc[i][r], KC, e.x));
                o01[r] += (floatx2){rv, rv} * eyz;
                o2[r]   = fmaf(rv, e.w, o2[r]);
            }
        }
        __syncthreads();   // readers of cur done; stage(cur^1) drained
    }
#undef STAGE

    // intra-wave reduce over the 16 n-lanes (xor 1,2,4,8 stay within kq group)
    float oacc[12];
#pragma unroll
    for (int r = 0; r < 4; ++r) {
        oacc[r * 3 + 0] = o01[r].x;
        oacc[r * 3 + 1] = o01[r].y;
        oacc[r * 3 + 2] = o2[r];
    }
#pragma unroll
    for (int i = 0; i < 12; ++i) {
        oacc[i] += __shfl_xor(oacc[i], 1);
        oacc[i] += __shfl_xor(oacc[i], 2);
        oacc[i] += __shfl_xor(oacc[i], 4);
        oacc[i] += __shfl_xor(oacc[i], 8);
    }

    // red aliases ep_s: safe, all ep reads completed before last barrier
    if (m < OUTD) {
#pragma unroll
        for (int r = 0; r < 4; ++r)
            red[w * 48 + kq * 12 + r * 3 + m] = oacc[r * 3 + m];
    }
    __syncthreads();

    // combine nt-halves: 2 tiles x 48 outputs
    if (tid < 96) {
        int tloc2 = tid / 48;
        int q     = tid % 48;
        int tile2 = blockIdx.x * 2 + tloc2;
        if (tile2 < ntile_total) {
            int idx = tile2 * 48 + q;
            if (idx < B * 3) {
                float s = red[(tloc2 * 2) * 48 + q] + red[(tloc2 * 2 + 1) * 48 + q] + bias[q % 3];
                out[idx] = s;
            }
        }
    }
}

extern "C" void kernel_launch(void* const* d_in, const int* in_sizes, int n_in,
                              void* d_out, int out_size, void* d_ws, size_t ws_size,
                              hipStream_t stream) {
    // inputs: 0=x (UNUSED by reference), 1=feats, 2=centers, 3=betas, 4=W, 5=b
    const float* feats   = (const float*)d_in[1];
    const float* centers = (const float*)d_in[2];
    const float* betas   = (const float*)d_in[3];
    const float* W       = (const float*)d_in[4];
    const float* bias    = (const float*)d_in[5];
    float* out = (float*)d_out;
    int B = in_sizes[1] / (LN * FD);

    short* PKB = (short*)d_ws;                       // 65536 shorts = 128 KB
    float* EPI = (float*)((char*)d_ws + 65536 * 2);  // 8192 floats = 32 KB

    prep<<<40, 256, 0, stream>>>(centers, betas, W, PKB, EPI);

    int tiles  = (B + 15) / 16;
    int blocks = (tiles + 1) / 2;
    rbf_mfma<<<blocks, 256, 0, stream>>>(feats, PKB, EPI, bias, out, B);
}